// Round 2
// baseline (2253.721 us; speedup 1.0000x reference)
//
#include <hip/hip_runtime.h>
#include <math.h>

#define DIMC 256
#define CO   516
#define NB   32
#define NH   64
#define NW   64
#define NPIX (NB*NH*NW)   // 131072
#define TP   16           // pixels per block in GEMM kernels

__device__ __forceinline__ float gelu_f(float x) {
    return 0.5f * x * (1.0f + erff(x * 0.7071067811865476f));
}

// ---------------------------------------------------------------------------
// Kernel 1: x_proj = x @ w_init + b_init.
//   q (cols 0..255)      -> qout (aliases d_out; k_final overwrites later)
//   context (256..511)   -> ctx
//   gates (512..515)     -> gates, clipped to [-1,1]
// Block: 256 threads, TP pixels staged in LDS. Thread t owns cols t, 256+t.
// Gate columns done in a 64-thread epilogue (4 cols x 16 pix dot products).
// ---------------------------------------------------------------------------
__global__ __launch_bounds__(256) void k_init(const float* __restrict__ x,
                                              const float* __restrict__ w_init,
                                              const float* __restrict__ b_init,
                                              float* __restrict__ qout,
                                              float* __restrict__ ctx,
                                              float* __restrict__ gates) {
    __shared__ float xs[TP][DIMC];
    const int t = threadIdx.x;
    const long p0 = (long)blockIdx.x * TP;
    for (int p = 0; p < TP; ++p)
        xs[p][t] = x[(p0 + p) * DIMC + t];
    __syncthreads();

    float acc0[TP], acc1[TP];
    #pragma unroll
    for (int p = 0; p < TP; ++p) { acc0[p] = 0.f; acc1[p] = 0.f; }

    for (int k = 0; k < DIMC; k += 4) {
        float wq[4], wc[4];
        #pragma unroll
        for (int j = 0; j < 4; ++j) {
            wq[j] = w_init[(k + j) * CO + t];
            wc[j] = w_init[(k + j) * CO + 256 + t];
        }
        #pragma unroll
        for (int p = 0; p < TP; ++p) {
            const float4 xv = *(const float4*)&xs[p][k];
            acc0[p] += xv.x * wq[0] + xv.y * wq[1] + xv.z * wq[2] + xv.w * wq[3];
            acc1[p] += xv.x * wc[0] + xv.y * wc[1] + xv.z * wc[2] + xv.w * wc[3];
        }
    }

    const float bq = b_init[t], bc = b_init[256 + t];
    for (int p = 0; p < TP; ++p) {
        qout[(p0 + p) * DIMC + t] = acc0[p] + bq;
        ctx[(p0 + p) * DIMC + t]  = acc1[p] + bc;
    }

    // gates: 4 cols x TP pixels, one (col,pix) pair per thread for t<64
    if (t < 4 * TP) {
        const int col = t & 3;
        const int p   = t >> 2;
        float g = b_init[512 + col];
        for (int k = 0; k < DIMC; k += 4) {
            const float4 xv = *(const float4*)&xs[p][k];
            g += xv.x * w_init[(k + 0) * CO + 512 + col]
               + xv.y * w_init[(k + 1) * CO + 512 + col]
               + xv.z * w_init[(k + 2) * CO + 512 + col]
               + xv.w * w_init[(k + 3) * CO + 512 + col];
        }
        g = fminf(1.f, fmaxf(-1.f, g));
        gates[(p0 + p) * 4 + col] = g;
    }
}

// ---------------------------------------------------------------------------
// Depthwise conv KSxKS (cross-correlation, zero pad KS/2) + GELU + gated
// accumulate into acc. Block: 256 threads = channels; strip of 16 output rows
// (fixed b, w). Weights in registers; input reused across sliding window.
// Grid: NB*NW*(NH/16) = 8192 blocks. bid -> hchunk(2b) | w(6b) | b(5b).
// ---------------------------------------------------------------------------
template<int KS, int LEVEL>
__global__ __launch_bounds__(256) void k_dwconv(const float* __restrict__ in,
                                                const float* __restrict__ kw,
                                                const float* __restrict__ gates,
                                                float* __restrict__ out,
                                                float* __restrict__ acc) {
    constexpr int P  = KS / 2;
    constexpr int TH = 16;
    const int c      = threadIdx.x;
    const int bid    = blockIdx.x;
    const int hchunk = bid & 3;
    const int w      = (bid >> 2) & 63;
    const int b      = bid >> 8;
    const int h0     = hchunk * TH;

    float wreg[KS * KS];
    #pragma unroll
    for (int i = 0; i < KS * KS; ++i) wreg[i] = kw[i * DIMC + c];

    float s[TH];
    #pragma unroll
    for (int j = 0; j < TH; ++j) s[j] = 0.f;

    const long base = (long)b * 4096 * DIMC;
    #pragma unroll
    for (int dx = 0; dx < KS; ++dx) {
        const int wx = w + dx - P;
        if (wx < 0 || wx >= NW) continue;
        #pragma unroll
        for (int i = 0; i < TH + 2 * P; ++i) {
            const int hy = h0 + i - P;
            if (hy < 0 || hy >= NH) continue;
            const float xv = in[base + ((long)hy * NW + wx) * DIMC + c];
            #pragma unroll
            for (int j = 0; j < TH; ++j) {
                const int dy = i - j;
                if (dy >= 0 && dy <= 2 * P)
                    s[j] += xv * wreg[dy * KS + dx];
            }
        }
    }

    #pragma unroll
    for (int j = 0; j < TH; ++j) {
        const int h = h0 + j;
        const long pix = (long)b * 4096 + h * NW + w;
        const float v = gelu_f(s[j]);
        out[pix * DIMC + c] = v;
        const float g = gates[pix * 4 + LEVEL];
        if (LEVEL == 0) acc[pix * DIMC + c] = v * g;
        else            acc[pix * DIMC + c] += v * g;
    }
}

// ---------------------------------------------------------------------------
// Global mean over H,W of ctx2, then tanh. Two stages.
// ---------------------------------------------------------------------------
__global__ __launch_bounds__(256) void k_mean_part(const float* __restrict__ ctx2,
                                                   float* __restrict__ partial) {
    const int c = threadIdx.x;
    const int bid = blockIdx.x;       // 0..1023
    const int b = bid >> 5, chunk = bid & 31;
    const long p0 = (long)b * 4096 + chunk * 128;
    float s = 0.f;
    for (int i = 0; i < 128; ++i) s += ctx2[(p0 + i) * DIMC + c];
    partial[(long)bid * DIMC + c] = s;
}

__global__ __launch_bounds__(256) void k_mean_fin(const float* __restrict__ partial,
                                                  float* __restrict__ gl) {
    const int c = threadIdx.x; const int b = blockIdx.x;
    float s = 0.f;
    for (int j = 0; j < 32; ++j) s += partial[((long)b * 32 + j) * DIMC + c];
    gl[b * DIMC + c] = tanhf(s * (1.f / 4096.f));
}

// ---------------------------------------------------------------------------
// Final: c_all = acc + gl[b]*g3; mod = clip(c_all@w_mod + b_mod);
// out = (clip(q)*mod) @ w_proj + b_proj.
// qout holds q on entry (written by k_init) and the final output on exit.
// Each element is read (into LDS product) strictly before it is written,
// within the same block; blocks touch disjoint pixels.
// ---------------------------------------------------------------------------
__global__ __launch_bounds__(256) void k_final(float* qout,
                                               const float* __restrict__ accb,
                                               const float* __restrict__ gates,
                                               const float* __restrict__ gl,
                                               const float* __restrict__ w_mod,
                                               const float* __restrict__ b_mod,
                                               const float* __restrict__ w_proj,
                                               const float* __restrict__ b_proj) {
    __shared__ float cs[TP][DIMC];
    const int t = threadIdx.x;
    const long p0 = (long)blockIdx.x * TP;
    const int b = (int)(p0 >> 12);   // TP=16 divides 4096 -> all pixels same image

    {
        const float glv = gl[b * DIMC + t];
        for (int p = 0; p < TP; ++p) {
            const float g3 = gates[(p0 + p) * 4 + 3];
            cs[p][t] = accb[(p0 + p) * DIMC + t] + glv * g3;
        }
    }
    __syncthreads();

    float m[TP];
    #pragma unroll
    for (int p = 0; p < TP; ++p) m[p] = 0.f;
    for (int k = 0; k < DIMC; k += 4) {
        float wv[4];
        #pragma unroll
        for (int j = 0; j < 4; ++j) wv[j] = w_mod[(k + j) * DIMC + t];
        #pragma unroll
        for (int p = 0; p < TP; ++p) {
            const float4 xv = *(const float4*)&cs[p][k];
            m[p] += xv.x * wv[0] + xv.y * wv[1] + xv.z * wv[2] + xv.w * wv[3];
        }
    }
    const float bm = b_mod[t];
    #pragma unroll
    for (int p = 0; p < TP; ++p)
        m[p] = fminf(100.f, fmaxf(-100.f, m[p] + bm));

    __syncthreads();
    for (int p = 0; p < TP; ++p) {
        float qv = qout[(p0 + p) * DIMC + t];
        qv = fminf(100.f, fmaxf(-100.f, qv));
        cs[p][t] = qv * m[p];
    }
    __syncthreads();

    float o[TP];
    #pragma unroll
    for (int p = 0; p < TP; ++p) o[p] = 0.f;
    for (int k = 0; k < DIMC; k += 4) {
        float wv[4];
        #pragma unroll
        for (int j = 0; j < 4; ++j) wv[j] = w_proj[(k + j) * DIMC + t];
        #pragma unroll
        for (int p = 0; p < TP; ++p) {
            const float4 xv = *(const float4*)&cs[p][k];
            o[p] += xv.x * wv[0] + xv.y * wv[1] + xv.z * wv[2] + xv.w * wv[3];
        }
    }
    const float bp = b_proj[t];
    for (int p = 0; p < TP; ++p)
        qout[(p0 + p) * DIMC + t] = o[p] + bp;
}

// ---------------------------------------------------------------------------
// Workspace budget: 3*NP + NPIX*4 + 1024*256 + 32*256 floats
//   = 3*128MiB + ~3.2MB  ~= 406 MB   (q lives in d_out, not ws)
// ---------------------------------------------------------------------------
extern "C" void kernel_launch(void* const* d_in, const int* in_sizes, int n_in,
                              void* d_out, int out_size, void* d_ws, size_t ws_size,
                              hipStream_t stream) {
    const float* x      = (const float*)d_in[0];
    const float* w_init = (const float*)d_in[1];
    const float* b_init = (const float*)d_in[2];
    const float* k0     = (const float*)d_in[3];
    const float* k1     = (const float*)d_in[4];
    const float* k2     = (const float*)d_in[5];
    const float* w_mod  = (const float*)d_in[6];
    const float* b_mod  = (const float*)d_in[7];
    const float* w_proj = (const float*)d_in[8];
    const float* b_proj = (const float*)d_in[9];
    float* qout = (float*)d_out;

    float* ws = (float*)d_ws;
    const long NP = (long)NPIX * DIMC;          // 33,554,432 floats
    float* bufA    = ws;
    float* bufB    = ws + NP;
    float* accb    = ws + 2 * NP;
    float* gates   = ws + 3 * NP;               // NPIX*4
    float* partial = gates + (long)NPIX * 4;    // 1024*256
    float* gl      = partial + 1024 * DIMC;     // 32*256

    k_init<<<NPIX / TP, 256, 0, stream>>>(x, w_init, b_init, qout, bufA, gates);
    k_dwconv<3, 0><<<8192, 256, 0, stream>>>(bufA, k0, gates, bufB, accb);
    k_dwconv<5, 1><<<8192, 256, 0, stream>>>(bufB, k1, gates, bufA, accb);
    k_dwconv<7, 2><<<8192, 256, 0, stream>>>(bufA, k2, gates, bufB, accb);
    k_mean_part<<<1024, 256, 0, stream>>>(bufB, partial);
    k_mean_fin<<<32, 256, 0, stream>>>(partial, gl);
    k_final<<<NPIX / TP, 256, 0, stream>>>(qout, accb, gates, gl,
                                           w_mod, b_mod, w_proj, b_proj);
}

// Round 3
// 1382.419 us; speedup vs baseline: 1.6303x; 1.6303x over previous
//
#include <hip/hip_runtime.h>
#include <math.h>

#define DIMC 256
#define CO   516
#define NB   32
#define NH   64
#define NW   64
#define NPIX (NB*NH*NW)   // 131072
#define PITCH 264         // LDS row pitch in shorts (256 + 8 pad)

typedef short short8 __attribute__((ext_vector_type(8)));
typedef float floatx4 __attribute__((ext_vector_type(4)));
typedef unsigned short us4 __attribute__((ext_vector_type(4)));

__device__ __forceinline__ float gelu_f(float x) {
    return 0.5f * x * (1.0f + erff(x * 0.7071067811865476f));
}
__device__ __forceinline__ float clip100(float v) {
    return fminf(100.f, fmaxf(-100.f, v));
}
// round-to-nearest-even split of fp32 into bf16 hi + bf16 lo (x ~= hi+lo, err ~2^-16|x|)
__device__ __forceinline__ void split2(float x, unsigned short& h, unsigned short& l) {
    unsigned int xb = __float_as_uint(x);
    unsigned int hb = (xb + 0x7fffu + ((xb >> 16) & 1u)) & 0xffff0000u;
    h = (unsigned short)(hb >> 16);
    float r = x - __uint_as_float(hb);
    unsigned int rb = __float_as_uint(r);
    l = (unsigned short)((rb + 0x7fffu + ((rb >> 16) & 1u)) >> 16);
}
__device__ __forceinline__ float bf2f(unsigned short h) {
    return __uint_as_float(((unsigned int)h) << 16);
}

// ---------------------------------------------------------------------------
// Weight prep: transpose + split to bf16 hi/lo.
//   wiT[n][k] from w_init[k][n] (n<512), wmT from w_mod, wpT from w_proj.
// Grid 1024 blocks x 256 threads (t = k).
// ---------------------------------------------------------------------------
__global__ __launch_bounds__(256) void k_prep(const float* __restrict__ w_init,
                                              const float* __restrict__ w_mod,
                                              const float* __restrict__ w_proj,
                                              unsigned short* wiT_h, unsigned short* wiT_l,
                                              unsigned short* wmT_h, unsigned short* wmT_l,
                                              unsigned short* wpT_h, unsigned short* wpT_l) {
    const int n = blockIdx.x;
    const int k = threadIdx.x;
    unsigned short h, l;
    if (n < 512) {
        split2(w_init[k * CO + n], h, l);
        wiT_h[n * 256 + k] = h; wiT_l[n * 256 + k] = l;
    } else if (n < 768) {
        const int nn = n - 512;
        split2(w_mod[k * 256 + nn], h, l);
        wmT_h[nn * 256 + k] = h; wmT_l[nn * 256 + k] = l;
    } else {
        const int nn = n - 768;
        split2(w_proj[k * 256 + nn], h, l);
        wpT_h[nn * 256 + k] = h; wpT_l[nn * 256 + k] = l;
    }
}

// ---------------------------------------------------------------------------
// k_init_mfma: x_proj = x @ w_init + b_init, split-bf16 MFMA.
// Block: 256 thr = 4 waves, 64-pixel tile. x tile split hi/lo into LDS.
// Two n-half passes (cols 0..255 -> qout, 256..511 -> ctx); wave w owns
// cols w*64..w*64+63 of each half (4x4 16x16 tiles, 3 MFMAs per k-step pair).
// Gates (cols 512..515) via per-thread dot-product epilogue from LDS.
// ---------------------------------------------------------------------------
__global__ __launch_bounds__(256) void k_init_mfma(const float* __restrict__ x,
                                                   const unsigned short* __restrict__ wiT_h,
                                                   const unsigned short* __restrict__ wiT_l,
                                                   const float* __restrict__ w_init_raw,
                                                   const float* __restrict__ b_init,
                                                   float* __restrict__ qout,
                                                   float* __restrict__ ctx,
                                                   float* __restrict__ gates) {
    __shared__ unsigned short Ah[64 * PITCH];
    __shared__ unsigned short Al[64 * PITCH];
    const int t = threadIdx.x;
    const long p0 = (long)blockIdx.x * 64;

    // stage x tile (64x256 fp32) -> hi/lo bf16 LDS
    for (int i = 0; i < 16; ++i) {
        const int idx = i * 256 + t;
        const int row = idx >> 6, c4 = idx & 63;
        const float4 v = ((const float4*)x)[(p0 + row) * 64 + c4];
        unsigned short h0,h1,h2,h3,l0,l1,l2,l3;
        split2(v.x,h0,l0); split2(v.y,h1,l1); split2(v.z,h2,l2); split2(v.w,h3,l3);
        *(us4*)&Ah[row * PITCH + c4 * 4] = (us4){h0,h1,h2,h3};
        *(us4*)&Al[row * PITCH + c4 * 4] = (us4){l0,l1,l2,l3};
    }
    __syncthreads();

    const int wv = t >> 6, lane = t & 63;
    const int l15 = lane & 15, quad = lane >> 4;

    for (int half = 0; half < 2; ++half) {
        const int ncol0 = half * 256 + wv * 64;   // global col base for this wave
        floatx4 acc[4][4];
        #pragma unroll
        for (int im = 0; im < 4; ++im)
            #pragma unroll
            for (int in_ = 0; in_ < 4; ++in_)
                acc[im][in_] = (floatx4){0.f, 0.f, 0.f, 0.f};

        for (int kk = 0; kk < 256; kk += 32) {
            short8 ah[4], al[4], bh[4], bl[4];
            #pragma unroll
            for (int im = 0; im < 4; ++im) {
                const int off = (im * 16 + l15) * PITCH + kk + quad * 8;
                ah[im] = *(const short8*)&Ah[off];
                al[im] = *(const short8*)&Al[off];
            }
            #pragma unroll
            for (int in_ = 0; in_ < 4; ++in_) {
                const int n = ncol0 + in_ * 16 + l15;
                const int off = n * 256 + kk + quad * 8;
                bh[in_] = *(const short8*)&wiT_h[off];
                bl[in_] = *(const short8*)&wiT_l[off];
            }
            #pragma unroll
            for (int im = 0; im < 4; ++im)
                #pragma unroll
                for (int in_ = 0; in_ < 4; ++in_) {
                    acc[im][in_] = __builtin_amdgcn_mfma_f32_16x16x32_bf16(ah[im], bh[in_], acc[im][in_], 0, 0, 0);
                    acc[im][in_] = __builtin_amdgcn_mfma_f32_16x16x32_bf16(ah[im], bl[in_], acc[im][in_], 0, 0, 0);
                    acc[im][in_] = __builtin_amdgcn_mfma_f32_16x16x32_bf16(al[im], bh[in_], acc[im][in_], 0, 0, 0);
                }
        }

        float* dst = half ? ctx : qout;
        #pragma unroll
        for (int in_ = 0; in_ < 4; ++in_) {
            const int colg = ncol0 + in_ * 16 + l15;       // 0..511 (b_init index)
            const int colw = (ncol0 & 255) + in_ * 16 + l15; // 0..255 within dst
            const float bi = b_init[colg];
            #pragma unroll
            for (int im = 0; im < 4; ++im)
                #pragma unroll
                for (int r = 0; r < 4; ++r) {
                    const int row = im * 16 + quad * 4 + r;
                    dst[(p0 + row) * 256 + colw] = acc[im][in_][r] + bi;
                }
        }
    }

    // gates epilogue: thread t -> pixel p=t>>2, gate col=t&3
    {
        const int p = t >> 2, col = t & 3;
        float g = b_init[512 + col];
        for (int k = 0; k < 256; k += 8) {
            const short8 hv = *(const short8*)&Ah[p * PITCH + k];
            const short8 lv = *(const short8*)&Al[p * PITCH + k];
            #pragma unroll
            for (int j = 0; j < 8; ++j) {
                const float xf = bf2f((unsigned short)hv[j]) + bf2f((unsigned short)lv[j]);
                g += xf * w_init_raw[(k + j) * CO + 512 + col];
            }
        }
        g = fminf(1.f, fmaxf(-1.f, g));
        gates[(p0 + p) * 4 + col] = g;
    }
}

// ---------------------------------------------------------------------------
// Depthwise conv KSxKS + GELU + gated accumulate (unchanged from R2).
// ---------------------------------------------------------------------------
template<int KS, int LEVEL>
__global__ __launch_bounds__(256) void k_dwconv(const float* __restrict__ in,
                                                const float* __restrict__ kw,
                                                const float* __restrict__ gates,
                                                float* __restrict__ out,
                                                float* __restrict__ acc) {
    constexpr int P  = KS / 2;
    constexpr int TH = 16;
    const int c      = threadIdx.x;
    const int bid    = blockIdx.x;
    const int hchunk = bid & 3;
    const int w      = (bid >> 2) & 63;
    const int b      = bid >> 8;
    const int h0     = hchunk * TH;

    float wreg[KS * KS];
    #pragma unroll
    for (int i = 0; i < KS * KS; ++i) wreg[i] = kw[i * DIMC + c];

    float s[TH];
    #pragma unroll
    for (int j = 0; j < TH; ++j) s[j] = 0.f;

    const long base = (long)b * 4096 * DIMC;
    #pragma unroll
    for (int dx = 0; dx < KS; ++dx) {
        const int wx = w + dx - P;
        if (wx < 0 || wx >= NW) continue;
        #pragma unroll
        for (int i = 0; i < TH + 2 * P; ++i) {
            const int hy = h0 + i - P;
            if (hy < 0 || hy >= NH) continue;
            const float xv = in[base + ((long)hy * NW + wx) * DIMC + c];
            #pragma unroll
            for (int j = 0; j < TH; ++j) {
                const int dy = i - j;
                if (dy >= 0 && dy <= 2 * P)
                    s[j] += xv * wreg[dy * KS + dx];
            }
        }
    }

    #pragma unroll
    for (int j = 0; j < TH; ++j) {
        const int h = h0 + j;
        const long pix = (long)b * 4096 + h * NW + w;
        const float v = gelu_f(s[j]);
        out[pix * DIMC + c] = v;
        const float g = gates[pix * 4 + LEVEL];
        if (LEVEL == 0) acc[pix * DIMC + c] = v * g;
        else            acc[pix * DIMC + c] += v * g;
    }
}

// ---------------------------------------------------------------------------
// Global mean over H,W of ctx2, then tanh.
// ---------------------------------------------------------------------------
__global__ __launch_bounds__(256) void k_mean_part(const float* __restrict__ ctx2,
                                                   float* __restrict__ partial) {
    const int c = threadIdx.x;
    const int bid = blockIdx.x;
    const int b = bid >> 5, chunk = bid & 31;
    const long p0 = (long)b * 4096 + chunk * 128;
    float s = 0.f;
    for (int i = 0; i < 128; ++i) s += ctx2[(p0 + i) * DIMC + c];
    partial[(long)bid * DIMC + c] = s;
}

__global__ __launch_bounds__(256) void k_mean_fin(const float* __restrict__ partial,
                                                  float* __restrict__ gl) {
    const int c = threadIdx.x; const int b = blockIdx.x;
    float s = 0.f;
    for (int j = 0; j < 32; ++j) s += partial[((long)b * 32 + j) * DIMC + c];
    gl[b * DIMC + c] = tanhf(s * (1.f / 4096.f));
}

// ---------------------------------------------------------------------------
// k_final_mfma: c_all = accb + gl*g3 (split to LDS); GEMM1 mod = c_all@w_mod;
// p = clip(q)*clip(mod+b_mod) (split back into same LDS); GEMM2
// out = p@w_proj + b_proj. qout aliases d_out (holds q on entry).
// ---------------------------------------------------------------------------
__global__ __launch_bounds__(256) void k_final_mfma(float* qout,
                                                    const float* __restrict__ accb,
                                                    const float* __restrict__ gates,
                                                    const float* __restrict__ gl,
                                                    const unsigned short* __restrict__ wmT_h,
                                                    const unsigned short* __restrict__ wmT_l,
                                                    const unsigned short* __restrict__ wpT_h,
                                                    const unsigned short* __restrict__ wpT_l,
                                                    const float* __restrict__ b_mod,
                                                    const float* __restrict__ b_proj) {
    __shared__ unsigned short Ah[64 * PITCH];
    __shared__ unsigned short Al[64 * PITCH];
    const int t = threadIdx.x;
    const long p0 = (long)blockIdx.x * 64;
    const int b = (int)(p0 >> 12);

    // stage c_all tile
    for (int i = 0; i < 16; ++i) {
        const int idx = i * 256 + t;
        const int row = idx >> 6, c4 = idx & 63;
        float4 v = ((const float4*)accb)[(p0 + row) * 64 + c4];
        const float g3 = gates[(p0 + row) * 4 + 3];
        const float4 gv = ((const float4*)gl)[b * 64 + c4];
        v.x += gv.x * g3; v.y += gv.y * g3; v.z += gv.z * g3; v.w += gv.w * g3;
        unsigned short h0,h1,h2,h3,l0,l1,l2,l3;
        split2(v.x,h0,l0); split2(v.y,h1,l1); split2(v.z,h2,l2); split2(v.w,h3,l3);
        *(us4*)&Ah[row * PITCH + c4 * 4] = (us4){h0,h1,h2,h3};
        *(us4*)&Al[row * PITCH + c4 * 4] = (us4){l0,l1,l2,l3};
    }
    __syncthreads();

    const int wv = t >> 6, lane = t & 63;
    const int l15 = lane & 15, quad = lane >> 4;
    const int ncol0 = wv * 64;

    floatx4 acc[4][4];
    #pragma unroll
    for (int im = 0; im < 4; ++im)
        #pragma unroll
        for (int in_ = 0; in_ < 4; ++in_)
            acc[im][in_] = (floatx4){0.f, 0.f, 0.f, 0.f};

    // GEMM1: mod = c_all @ w_mod
    for (int kk = 0; kk < 256; kk += 32) {
        short8 ah[4], al[4], bh[4], bl[4];
        #pragma unroll
        for (int im = 0; im < 4; ++im) {
            const int off = (im * 16 + l15) * PITCH + kk + quad * 8;
            ah[im] = *(const short8*)&Ah[off];
            al[im] = *(const short8*)&Al[off];
        }
        #pragma unroll
        for (int in_ = 0; in_ < 4; ++in_) {
            const int off = (ncol0 + in_ * 16 + l15) * 256 + kk + quad * 8;
            bh[in_] = *(const short8*)&wmT_h[off];
            bl[in_] = *(const short8*)&wmT_l[off];
        }
        #pragma unroll
        for (int im = 0; im < 4; ++im)
            #pragma unroll
            for (int in_ = 0; in_ < 4; ++in_) {
                acc[im][in_] = __builtin_amdgcn_mfma_f32_16x16x32_bf16(ah[im], bh[in_], acc[im][in_], 0, 0, 0);
                acc[im][in_] = __builtin_amdgcn_mfma_f32_16x16x32_bf16(ah[im], bl[in_], acc[im][in_], 0, 0, 0);
                acc[im][in_] = __builtin_amdgcn_mfma_f32_16x16x32_bf16(al[im], bh[in_], acc[im][in_], 0, 0, 0);
            }
    }
    __syncthreads();   // all GEMM1 A-reads complete before overwrite

    // epilogue1: p = clip(q)*clip(mod + b_mod) -> LDS hi/lo
    #pragma unroll
    for (int in_ = 0; in_ < 4; ++in_) {
        const int col = ncol0 + in_ * 16 + l15;
        const float bm = b_mod[col];
        #pragma unroll
        for (int im = 0; im < 4; ++im)
            #pragma unroll
            for (int r = 0; r < 4; ++r) {
                const int row = im * 16 + quad * 4 + r;
                const float m = clip100(acc[im][in_][r] + bm);
                const float qv = clip100(qout[(p0 + row) * 256 + col]);
                unsigned short h, l;
                split2(qv * m, h, l);
                Ah[row * PITCH + col] = h;
                Al[row * PITCH + col] = l;
            }
    }
    __syncthreads();

    // GEMM2: out = p @ w_proj
    #pragma unroll
    for (int im = 0; im < 4; ++im)
        #pragma unroll
        for (int in_ = 0; in_ < 4; ++in_)
            acc[im][in_] = (floatx4){0.f, 0.f, 0.f, 0.f};

    for (int kk = 0; kk < 256; kk += 32) {
        short8 ah[4], al[4], bh[4], bl[4];
        #pragma unroll
        for (int im = 0; im < 4; ++im) {
            const int off = (im * 16 + l15) * PITCH + kk + quad * 8;
            ah[im] = *(const short8*)&Ah[off];
            al[im] = *(const short8*)&Al[off];
        }
        #pragma unroll
        for (int in_ = 0; in_ < 4; ++in_) {
            const int off = (ncol0 + in_ * 16 + l15) * 256 + kk + quad * 8;
            bh[in_] = *(const short8*)&wpT_h[off];
            bl[in_] = *(const short8*)&wpT_l[off];
        }
        #pragma unroll
        for (int im = 0; im < 4; ++im)
            #pragma unroll
            for (int in_ = 0; in_ < 4; ++in_) {
                acc[im][in_] = __builtin_amdgcn_mfma_f32_16x16x32_bf16(ah[im], bh[in_], acc[im][in_], 0, 0, 0);
                acc[im][in_] = __builtin_amdgcn_mfma_f32_16x16x32_bf16(ah[im], bl[in_], acc[im][in_], 0, 0, 0);
                acc[im][in_] = __builtin_amdgcn_mfma_f32_16x16x32_bf16(al[im], bh[in_], acc[im][in_], 0, 0, 0);
            }
    }

    // epilogue2: out = acc + b_proj
    #pragma unroll
    for (int in_ = 0; in_ < 4; ++in_) {
        const int col = ncol0 + in_ * 16 + l15;
        const float bp = b_proj[col];
        #pragma unroll
        for (int im = 0; im < 4; ++im)
            #pragma unroll
            for (int r = 0; r < 4; ++r) {
                const int row = im * 16 + quad * 4 + r;
                qout[(p0 + row) * 256 + col] = acc[im][in_][r] + bp;
            }
    }
}

// ---------------------------------------------------------------------------
extern "C" void kernel_launch(void* const* d_in, const int* in_sizes, int n_in,
                              void* d_out, int out_size, void* d_ws, size_t ws_size,
                              hipStream_t stream) {
    const float* x      = (const float*)d_in[0];
    const float* w_init = (const float*)d_in[1];
    const float* b_init = (const float*)d_in[2];
    const float* k0     = (const float*)d_in[3];
    const float* k1     = (const float*)d_in[4];
    const float* k2     = (const float*)d_in[5];
    const float* w_mod  = (const float*)d_in[6];
    const float* b_mod  = (const float*)d_in[7];
    const float* w_proj = (const float*)d_in[8];
    const float* b_proj = (const float*)d_in[9];
    float* qout = (float*)d_out;

    float* ws = (float*)d_ws;
    const long NP = (long)NPIX * DIMC;
    float* bufA    = ws;
    float* bufB    = ws + NP;
    float* accb    = ws + 2 * NP;
    float* gates   = ws + 3 * NP;                 // NPIX*4 floats
    float* partial = gates + (long)NPIX * 4;      // 1024*256
    float* gl      = partial + 1024 * DIMC;       // 32*256
    unsigned short* wiT_h = (unsigned short*)(gl + 32 * DIMC);
    unsigned short* wiT_l = wiT_h + 512 * 256;
    unsigned short* wmT_h = wiT_l + 512 * 256;
    unsigned short* wmT_l = wmT_h + 256 * 256;
    unsigned short* wpT_h = wmT_l + 256 * 256;
    unsigned short* wpT_l = wpT_h + 256 * 256;

    k_prep<<<1024, 256, 0, stream>>>(w_init, w_mod, w_proj,
                                     wiT_h, wiT_l, wmT_h, wmT_l, wpT_h, wpT_l);
    k_init_mfma<<<NPIX / 64, 256, 0, stream>>>(x, wiT_h, wiT_l, w_init, b_init,
                                               qout, bufA, gates);
    k_dwconv<3, 0><<<8192, 256, 0, stream>>>(bufA, k0, gates, bufB, accb);
    k_dwconv<5, 1><<<8192, 256, 0, stream>>>(bufB, k1, gates, bufA, accb);
    k_dwconv<7, 2><<<8192, 256, 0, stream>>>(bufA, k2, gates, bufB, accb);
    k_mean_part<<<1024, 256, 0, stream>>>(bufB, partial);
    k_mean_fin<<<32, 256, 0, stream>>>(partial, gl);
    k_final_mfma<<<NPIX / 64, 256, 0, stream>>>(qout, accb, gates, gl,
                                                wmT_h, wmT_l, wpT_h, wpT_l,
                                                b_mod, b_proj);
}

// Round 4
// 1117.959 us; speedup vs baseline: 2.0159x; 1.2366x over previous
//
#include <hip/hip_runtime.h>
#include <math.h>

#define DIMC 256
#define CO   516
#define NB   32
#define NH   64
#define NW   64
#define NPIX (NB*NH*NW)   // 131072
#define PITCH 264         // k_final/k_init LDS row pitch in shorts (256 + 8 pad)
#define CP    76          // conv LDS pitch (floats): %4==0, 4*CP%32!=0
#define CROWS 72          // 64 + 2*4 halo

typedef short short8 __attribute__((ext_vector_type(8)));
typedef float floatx4 __attribute__((ext_vector_type(4)));
typedef unsigned short us4 __attribute__((ext_vector_type(4)));

__device__ __forceinline__ float gelu_f(float x) {
    return 0.5f * x * (1.0f + erff(x * 0.7071067811865476f));
}
__device__ __forceinline__ float clip100(float v) {
    return fminf(100.f, fmaxf(-100.f, v));
}
// round-to-nearest-even split of fp32 into bf16 hi + bf16 lo (x ~= hi+lo)
__device__ __forceinline__ void split2(float x, unsigned short& h, unsigned short& l) {
    unsigned int xb = __float_as_uint(x);
    unsigned int hb = (xb + 0x7fffu + ((xb >> 16) & 1u)) & 0xffff0000u;
    h = (unsigned short)(hb >> 16);
    float r = x - __uint_as_float(hb);
    unsigned int rb = __float_as_uint(r);
    l = (unsigned short)((rb + 0x7fffu + ((rb >> 16) & 1u)) >> 16);
}
__device__ __forceinline__ float bf2f(unsigned short h) {
    return __uint_as_float(((unsigned int)h) << 16);
}

// ---------------------------------------------------------------------------
// Weight prep: transpose + split to bf16 hi/lo.
// ---------------------------------------------------------------------------
__global__ __launch_bounds__(256) void k_prep(const float* __restrict__ w_init,
                                              const float* __restrict__ w_mod,
                                              const float* __restrict__ w_proj,
                                              unsigned short* wiT_h, unsigned short* wiT_l,
                                              unsigned short* wmT_h, unsigned short* wmT_l,
                                              unsigned short* wpT_h, unsigned short* wpT_l) {
    const int n = blockIdx.x;
    const int k = threadIdx.x;
    unsigned short h, l;
    if (n < 512) {
        split2(w_init[k * CO + n], h, l);
        wiT_h[n * 256 + k] = h; wiT_l[n * 256 + k] = l;
    } else if (n < 768) {
        const int nn = n - 512;
        split2(w_mod[k * 256 + nn], h, l);
        wmT_h[nn * 256 + k] = h; wmT_l[nn * 256 + k] = l;
    } else {
        const int nn = n - 768;
        split2(w_proj[k * 256 + nn], h, l);
        wpT_h[nn * 256 + k] = h; wpT_l[nn * 256 + k] = l;
    }
}

// ---------------------------------------------------------------------------
// k_init_mfma: x_proj = x @ w_init + b_init (split-bf16 MFMA).
//   q (cols 0..255)    -> qout [pix][c]  (aliases d_out)
//   ctx (cols 256..511)-> ctxp PLANAR [b][c][4096] (feeds fused conv)
//   gates (512..515)   -> gates [pix][4], clipped
// ---------------------------------------------------------------------------
__global__ __launch_bounds__(256) void k_init_mfma(const float* __restrict__ x,
                                                   const unsigned short* __restrict__ wiT_h,
                                                   const unsigned short* __restrict__ wiT_l,
                                                   const float* __restrict__ w_init_raw,
                                                   const float* __restrict__ b_init,
                                                   float* __restrict__ qout,
                                                   float* __restrict__ ctxp,
                                                   float* __restrict__ gates) {
    __shared__ unsigned short Ah[64 * PITCH];
    __shared__ unsigned short Al[64 * PITCH];
    const int t = threadIdx.x;
    const long p0 = (long)blockIdx.x * 64;
    const int bb = (int)(p0 >> 12);
    const int pl = (int)(p0 & 4095);

    for (int i = 0; i < 16; ++i) {
        const int idx = i * 256 + t;
        const int row = idx >> 6, c4 = idx & 63;
        const float4 v = ((const float4*)x)[(p0 + row) * 64 + c4];
        unsigned short h0,h1,h2,h3,l0,l1,l2,l3;
        split2(v.x,h0,l0); split2(v.y,h1,l1); split2(v.z,h2,l2); split2(v.w,h3,l3);
        *(us4*)&Ah[row * PITCH + c4 * 4] = (us4){h0,h1,h2,h3};
        *(us4*)&Al[row * PITCH + c4 * 4] = (us4){l0,l1,l2,l3};
    }
    __syncthreads();

    const int wv = t >> 6, lane = t & 63;
    const int l15 = lane & 15, quad = lane >> 4;

    for (int half = 0; half < 2; ++half) {
        const int ncol0 = half * 256 + wv * 64;
        floatx4 acc[4][4];
        #pragma unroll
        for (int im = 0; im < 4; ++im)
            #pragma unroll
            for (int in_ = 0; in_ < 4; ++in_)
                acc[im][in_] = (floatx4){0.f, 0.f, 0.f, 0.f};

        for (int kk = 0; kk < 256; kk += 32) {
            short8 ah[4], al[4], bh[4], bl[4];
            #pragma unroll
            for (int im = 0; im < 4; ++im) {
                const int off = (im * 16 + l15) * PITCH + kk + quad * 8;
                ah[im] = *(const short8*)&Ah[off];
                al[im] = *(const short8*)&Al[off];
            }
            #pragma unroll
            for (int in_ = 0; in_ < 4; ++in_) {
                const int n = ncol0 + in_ * 16 + l15;
                const int off = n * 256 + kk + quad * 8;
                bh[in_] = *(const short8*)&wiT_h[off];
                bl[in_] = *(const short8*)&wiT_l[off];
            }
            #pragma unroll
            for (int im = 0; im < 4; ++im)
                #pragma unroll
                for (int in_ = 0; in_ < 4; ++in_) {
                    acc[im][in_] = __builtin_amdgcn_mfma_f32_16x16x32_bf16(ah[im], bh[in_], acc[im][in_], 0, 0, 0);
                    acc[im][in_] = __builtin_amdgcn_mfma_f32_16x16x32_bf16(ah[im], bl[in_], acc[im][in_], 0, 0, 0);
                    acc[im][in_] = __builtin_amdgcn_mfma_f32_16x16x32_bf16(al[im], bh[in_], acc[im][in_], 0, 0, 0);
                }
        }

        if (half == 0) {
            #pragma unroll
            for (int in_ = 0; in_ < 4; ++in_) {
                const int col = wv * 64 + in_ * 16 + l15;
                const float bi = b_init[col];
                #pragma unroll
                for (int im = 0; im < 4; ++im)
                    #pragma unroll
                    for (int r = 0; r < 4; ++r) {
                        const int row = im * 16 + quad * 4 + r;
                        qout[(p0 + row) * 256 + col] = acc[im][in_][r] + bi;
                    }
            }
        } else {
            // planar store: 4 consecutive pixels per float4
            #pragma unroll
            for (int in_ = 0; in_ < 4; ++in_) {
                const int col = wv * 64 + in_ * 16 + l15;     // channel
                const float bi = b_init[256 + col];
                #pragma unroll
                for (int im = 0; im < 4; ++im) {
                    float4 o;
                    o.x = acc[im][in_][0] + bi;
                    o.y = acc[im][in_][1] + bi;
                    o.z = acc[im][in_][2] + bi;
                    o.w = acc[im][in_][3] + bi;
                    *(float4*)&ctxp[((size_t)bb * 256 + col) * 4096 + pl + im * 16 + quad * 4] = o;
                }
            }
        }
    }

    // gates epilogue: thread t -> pixel p=t>>2, gate col=t&3
    {
        const int p = t >> 2, col = t & 3;
        float g = b_init[512 + col];
        for (int k = 0; k < 256; k += 8) {
            const short8 hv = *(const short8*)&Ah[p * PITCH + k];
            const short8 lv = *(const short8*)&Al[p * PITCH + k];
            #pragma unroll
            for (int j = 0; j < 8; ++j) {
                const float xf = bf2f((unsigned short)hv[j]) + bf2f((unsigned short)lv[j]);
                g += xf * w_init_raw[(k + j) * CO + 512 + col];
            }
        }
        g = fminf(1.f, fmaxf(-1.f, g));
        gates[(p0 + p) * 4 + col] = g;
    }
}

// ---------------------------------------------------------------------------
// conv_level: 4x4 output patch at (ry0,cx0) from LDS plane I (halo 4, pitch CP).
// Weights for this block's channel are uniform -> SGPRs. Returns GELU'd v[16].
// ---------------------------------------------------------------------------
template<int KS>
__device__ __forceinline__ void conv_level(const float* __restrict__ kwp,
                                           const float* __restrict__ I,
                                           int ry0, int cx0, float v[16]) {
    constexpr int P = KS / 2;
    constexpr int RWIN = 4 + 2 * P;
    float wk[KS * KS];
    #pragma unroll
    for (int i = 0; i < KS * KS; ++i) wk[i] = kwp[i * 256];

    float4 rb[RWIN][3];
    #pragma unroll
    for (int r = 0; r < 2 * P; ++r) {
        const int base = (ry0 + r - P + 4) * CP + cx0;
        rb[r][0] = *(const float4*)&I[base];
        rb[r][1] = *(const float4*)&I[base + 4];
        rb[r][2] = *(const float4*)&I[base + 8];
    }
    #pragma unroll
    for (int j = 0; j < 4; ++j) {
        {
            const int r = j + 2 * P;
            const int base = (ry0 + r - P + 4) * CP + cx0;
            rb[r][0] = *(const float4*)&I[base];
            rb[r][1] = *(const float4*)&I[base + 4];
            rb[r][2] = *(const float4*)&I[base + 8];
        }
        float s0 = 0.f, s1 = 0.f, s2 = 0.f, s3 = 0.f;
        #pragma unroll
        for (int dy = 0; dy < KS; ++dy) {
            const float* rw = (const float*)&rb[j + dy][0];   // 12 floats, cols cx0-4..cx0+7
            #pragma unroll
            for (int dx = 0; dx < KS; ++dx) {
                const float wgt = wk[dy * KS + dx];
                s0 += rw[4 - P + 0 + dx] * wgt;
                s1 += rw[4 - P + 1 + dx] * wgt;
                s2 += rw[4 - P + 2 + dx] * wgt;
                s3 += rw[4 - P + 3 + dx] * wgt;
            }
        }
        v[j * 4 + 0] = gelu_f(s0);
        v[j * 4 + 1] = gelu_f(s1);
        v[j * 4 + 2] = gelu_f(s2);
        v[j * 4 + 3] = gelu_f(s3);
    }
}

// ---------------------------------------------------------------------------
// k_conv_fused: one block per (b,c) 64x64 plane. Full conv chain in LDS:
//   t1 = gelu(conv3(t0)); t2 = gelu(conv5(t1)); t3 = gelu(conv7(t2))
//   c_all = t1*g0 + t2*g1 + t3*g2 + tanh(mean(t3))*g3   (mean is in-block!)
// Reads ctxp planar, writes c_allp planar. No intermediate HBM traffic.
// ---------------------------------------------------------------------------
__global__ __launch_bounds__(256) void k_conv_fused(const float* __restrict__ ctxp,
                                                    const float* __restrict__ k0,
                                                    const float* __restrict__ k1,
                                                    const float* __restrict__ k2,
                                                    const float* __restrict__ gates,
                                                    float* __restrict__ c_allp) {
    __shared__ float X[CROWS * CP];
    __shared__ float Y[CROWS * CP];
    const int t = threadIdx.x;
    const int bc = blockIdx.x;            // b*256 + c
    const int b = bc >> 8, c = bc & 255;
    const float* src = ctxp + (size_t)bc * 4096;

    for (int i = t; i < CROWS * CP; i += 256) { X[i] = 0.f; Y[i] = 0.f; }
    __syncthreads();
    #pragma unroll
    for (int i = 0; i < 4; ++i) {
        const int p = i * 1024 + t * 4;
        const float4 vv = *(const float4*)&src[p];
        *(float4*)&X[((p >> 6) + 4) * CP + (p & 63) + 4] = vv;
    }
    __syncthreads();

    const int px = t & 15, py = t >> 4;
    const int cx0 = px * 4, ry0 = py * 4;
    const float* gbase = gates + (size_t)b * 4096 * 4;

    float acc[16], v[16];

    // level 0: 3x3 from X, write t1 -> Y
    conv_level<3>(k0 + c, X, ry0, cx0, v);
    #pragma unroll
    for (int j = 0; j < 4; ++j) {
        *(float4*)&Y[(ry0 + j + 4) * CP + cx0 + 4] = *(float4*)&v[j * 4];
        #pragma unroll
        for (int i2 = 0; i2 < 4; ++i2)
            acc[j * 4 + i2] = v[j * 4 + i2] * gbase[((ry0 + j) * 64 + cx0 + i2) * 4 + 0];
    }
    __syncthreads();

    // level 1: 5x5 from Y, write t2 -> X
    conv_level<5>(k1 + c, Y, ry0, cx0, v);
    #pragma unroll
    for (int j = 0; j < 4; ++j) {
        *(float4*)&X[(ry0 + j + 4) * CP + cx0 + 4] = *(float4*)&v[j * 4];
        #pragma unroll
        for (int i2 = 0; i2 < 4; ++i2)
            acc[j * 4 + i2] += v[j * 4 + i2] * gbase[((ry0 + j) * 64 + cx0 + i2) * 4 + 1];
    }
    __syncthreads();

    // level 2: 7x7 from X, t3 stays in registers
    conv_level<7>(k2 + c, X, ry0, cx0, v);
    float vsum = 0.f;
    #pragma unroll
    for (int j = 0; j < 4; ++j)
        #pragma unroll
        for (int i2 = 0; i2 < 4; ++i2) {
            acc[j * 4 + i2] += v[j * 4 + i2] * gbase[((ry0 + j) * 64 + cx0 + i2) * 4 + 2];
            vsum += v[j * 4 + i2];
        }

    // in-block mean of t3 -> tanh -> gl (X reused as scratch after barrier)
    __syncthreads();
    X[t] = vsum;
    __syncthreads();
    if (t < 64) {
        float s = X[t] + X[t + 64] + X[t + 128] + X[t + 192];
        #pragma unroll
        for (int off = 32; off >= 1; off >>= 1)
            s += __shfl_down(s, off, 64);
        if (t == 0) X[0] = tanhf(s * (1.f / 4096.f));
    }
    __syncthreads();
    const float gl = X[0];

    float* dst = c_allp + (size_t)bc * 4096;
    #pragma unroll
    for (int j = 0; j < 4; ++j) {
        float4 o;
        o.x = acc[j * 4 + 0] + gl * gbase[((ry0 + j) * 64 + cx0 + 0) * 4 + 3];
        o.y = acc[j * 4 + 1] + gl * gbase[((ry0 + j) * 64 + cx0 + 1) * 4 + 3];
        o.z = acc[j * 4 + 2] + gl * gbase[((ry0 + j) * 64 + cx0 + 2) * 4 + 3];
        o.w = acc[j * 4 + 3] + gl * gbase[((ry0 + j) * 64 + cx0 + 3) * 4 + 3];
        *(float4*)&dst[(ry0 + j) * 64 + cx0] = o;
    }
}

// ---------------------------------------------------------------------------
// k_final_mfma: stage c_allp (planar -> LDS transpose, split bf16); GEMM1
// mod = c_all@w_mod; p = clip(q)*clip(mod+b_mod); GEMM2 out = p@w_proj+b_proj.
// qout aliases d_out (holds q on entry).
// ---------------------------------------------------------------------------
__global__ __launch_bounds__(256) void k_final_mfma(float* qout,
                                                    const float* __restrict__ c_allp,
                                                    const unsigned short* __restrict__ wmT_h,
                                                    const unsigned short* __restrict__ wmT_l,
                                                    const unsigned short* __restrict__ wpT_h,
                                                    const unsigned short* __restrict__ wpT_l,
                                                    const float* __restrict__ b_mod,
                                                    const float* __restrict__ b_proj) {
    __shared__ unsigned short Ah[64 * PITCH];
    __shared__ unsigned short Al[64 * PITCH];
    const int t = threadIdx.x;
    const long p0 = (long)blockIdx.x * 64;
    const int b = (int)(p0 >> 12);
    const int pl = (int)(p0 & 4095);

    // transpose-stage: thread t = channel t, 64 consecutive pixels
    {
        const float* src = c_allp + ((size_t)b * 256 + t) * 4096 + pl;
        #pragma unroll
        for (int i = 0; i < 16; ++i) {
            const float4 vv = *(const float4*)&src[i * 4];
            unsigned short h, l;
            split2(vv.x, h, l); Ah[(i*4+0)*PITCH + t] = h; Al[(i*4+0)*PITCH + t] = l;
            split2(vv.y, h, l); Ah[(i*4+1)*PITCH + t] = h; Al[(i*4+1)*PITCH + t] = l;
            split2(vv.z, h, l); Ah[(i*4+2)*PITCH + t] = h; Al[(i*4+2)*PITCH + t] = l;
            split2(vv.w, h, l); Ah[(i*4+3)*PITCH + t] = h; Al[(i*4+3)*PITCH + t] = l;
        }
    }
    __syncthreads();

    const int wv = t >> 6, lane = t & 63;
    const int l15 = lane & 15, quad = lane >> 4;
    const int ncol0 = wv * 64;

    floatx4 acc[4][4];
    #pragma unroll
    for (int im = 0; im < 4; ++im)
        #pragma unroll
        for (int in_ = 0; in_ < 4; ++in_)
            acc[im][in_] = (floatx4){0.f, 0.f, 0.f, 0.f};

    for (int kk = 0; kk < 256; kk += 32) {
        short8 ah[4], al[4], bh[4], bl[4];
        #pragma unroll
        for (int im = 0; im < 4; ++im) {
            const int off = (im * 16 + l15) * PITCH + kk + quad * 8;
            ah[im] = *(const short8*)&Ah[off];
            al[im] = *(const short8*)&Al[off];
        }
        #pragma unroll
        for (int in_ = 0; in_ < 4; ++in_) {
            const int off = (ncol0 + in_ * 16 + l15) * 256 + kk + quad * 8;
            bh[in_] = *(const short8*)&wmT_h[off];
            bl[in_] = *(const short8*)&wmT_l[off];
        }
        #pragma unroll
        for (int im = 0; im < 4; ++im)
            #pragma unroll
            for (int in_ = 0; in_ < 4; ++in_) {
                acc[im][in_] = __builtin_amdgcn_mfma_f32_16x16x32_bf16(ah[im], bh[in_], acc[im][in_], 0, 0, 0);
                acc[im][in_] = __builtin_amdgcn_mfma_f32_16x16x32_bf16(ah[im], bl[in_], acc[im][in_], 0, 0, 0);
                acc[im][in_] = __builtin_amdgcn_mfma_f32_16x16x32_bf16(al[im], bh[in_], acc[im][in_], 0, 0, 0);
            }
    }
    __syncthreads();

    // epilogue1: p = clip(q)*clip(mod + b_mod) -> LDS hi/lo
    #pragma unroll
    for (int in_ = 0; in_ < 4; ++in_) {
        const int col = ncol0 + in_ * 16 + l15;
        const float bm = b_mod[col];
        #pragma unroll
        for (int im = 0; im < 4; ++im)
            #pragma unroll
            for (int r = 0; r < 4; ++r) {
                const int row = im * 16 + quad * 4 + r;
                const float m = clip100(acc[im][in_][r] + bm);
                const float qv = clip100(qout[(p0 + row) * 256 + col]);
                unsigned short h, l;
                split2(qv * m, h, l);
                Ah[row * PITCH + col] = h;
                Al[row * PITCH + col] = l;
            }
    }
    __syncthreads();

    #pragma unroll
    for (int im = 0; im < 4; ++im)
        #pragma unroll
        for (int in_ = 0; in_ < 4; ++in_)
            acc[im][in_] = (floatx4){0.f, 0.f, 0.f, 0.f};

    for (int kk = 0; kk < 256; kk += 32) {
        short8 ah[4], al[4], bh[4], bl[4];
        #pragma unroll
        for (int im = 0; im < 4; ++im) {
            const int off = (im * 16 + l15) * PITCH + kk + quad * 8;
            ah[im] = *(const short8*)&Ah[off];
            al[im] = *(const short8*)&Al[off];
        }
        #pragma unroll
        for (int in_ = 0; in_ < 4; ++in_) {
            const int off = (ncol0 + in_ * 16 + l15) * 256 + kk + quad * 8;
            bh[in_] = *(const short8*)&wpT_h[off];
            bl[in_] = *(const short8*)&wpT_l[off];
        }
        #pragma unroll
        for (int im = 0; im < 4; ++im)
            #pragma unroll
            for (int in_ = 0; in_ < 4; ++in_) {
                acc[im][in_] = __builtin_amdgcn_mfma_f32_16x16x32_bf16(ah[im], bh[in_], acc[im][in_], 0, 0, 0);
                acc[im][in_] = __builtin_amdgcn_mfma_f32_16x16x32_bf16(ah[im], bl[in_], acc[im][in_], 0, 0, 0);
                acc[im][in_] = __builtin_amdgcn_mfma_f32_16x16x32_bf16(al[im], bh[in_], acc[im][in_], 0, 0, 0);
            }
    }

    #pragma unroll
    for (int in_ = 0; in_ < 4; ++in_) {
        const int col = ncol0 + in_ * 16 + l15;
        const float bp = b_proj[col];
        #pragma unroll
        for (int im = 0; im < 4; ++im)
            #pragma unroll
            for (int r = 0; r < 4; ++r) {
                const int row = im * 16 + quad * 4 + r;
                qout[(p0 + row) * 256 + col] = acc[im][in_][r] + bp;
            }
    }
}

// ---------------------------------------------------------------------------
extern "C" void kernel_launch(void* const* d_in, const int* in_sizes, int n_in,
                              void* d_out, int out_size, void* d_ws, size_t ws_size,
                              hipStream_t stream) {
    const float* x      = (const float*)d_in[0];
    const float* w_init = (const float*)d_in[1];
    const float* b_init = (const float*)d_in[2];
    const float* k0     = (const float*)d_in[3];
    const float* k1     = (const float*)d_in[4];
    const float* k2     = (const float*)d_in[5];
    const float* w_mod  = (const float*)d_in[6];
    const float* b_mod  = (const float*)d_in[7];
    const float* w_proj = (const float*)d_in[8];
    const float* b_proj = (const float*)d_in[9];
    float* qout = (float*)d_out;

    float* ws = (float*)d_ws;
    const long NP = (long)NPIX * DIMC;
    float* ctxp    = ws;                          // planar [b][c][4096]
    float* c_allp  = ws + NP;                     // planar [b][c][4096]
    float* gates   = ws + 2 * NP;                 // NPIX*4 floats
    unsigned short* wiT_h = (unsigned short*)(gates + (long)NPIX * 4);
    unsigned short* wiT_l = wiT_h + 512 * 256;
    unsigned short* wmT_h = wiT_l + 512 * 256;
    unsigned short* wmT_l = wmT_h + 256 * 256;
    unsigned short* wpT_h = wmT_l + 256 * 256;
    unsigned short* wpT_l = wpT_h + 256 * 256;

    k_prep<<<1024, 256, 0, stream>>>(w_init, w_mod, w_proj,
                                     wiT_h, wiT_l, wmT_h, wmT_l, wpT_h, wpT_l);
    k_init_mfma<<<NPIX / 64, 256, 0, stream>>>(x, wiT_h, wiT_l, w_init, b_init,
                                               qout, ctxp, gates);
    k_conv_fused<<<NB * 256, 256, 0, stream>>>(ctxp, k0, k1, k2, gates, c_allp);
    k_final_mfma<<<NPIX / 64, 256, 0, stream>>>(qout, c_allp,
                                                wmT_h, wmT_l, wpT_h, wpT_l,
                                                b_mod, b_proj);
}